// Round 9
// baseline (684.862 us; speedup 1.0000x reference)
//
#include <hip/hip_runtime.h>
#include <hip/hip_bf16.h>
#include <math.h>

#define T_TOK 8192
#define DM 1024
#define DF 4096
#define NE 8
#define MAXT 72    // max 256-row tiles: 64 full + 7 partials + slack

typedef __attribute__((ext_vector_type(4))) float  f32x4;
typedef __attribute__((ext_vector_type(8))) short  s16x8;
typedef __attribute__((ext_vector_type(8))) unsigned short u16x8;
typedef __attribute__((ext_vector_type(4))) unsigned short u16x4;

__device__ __forceinline__ unsigned short f2bf(float f) {
    unsigned int u = __builtin_bit_cast(unsigned int, f);
    u = (u + 0x7FFFu + ((u >> 16) & 1u)) >> 16;
    return (unsigned short)u;
}

#define GLDS16(gptr, lptr)                                                         \
    __builtin_amdgcn_global_load_lds(                                              \
        (const __attribute__((address_space(1))) void*)(gptr),                     \
        (__attribute__((address_space(3))) void*)(lptr), 16, 0, 0)

#define BAR() asm volatile("s_barrier" ::: "memory")

template<int W>
__device__ __forceinline__ void waitvm() {
    if constexpr (W == 6)      asm volatile("s_waitcnt vmcnt(6)" ::: "memory");
    else if constexpr (W == 3) asm volatile("s_waitcnt vmcnt(3)" ::: "memory");
    else                       asm volatile("s_waitcnt vmcnt(0)" ::: "memory");
}

// ------- Routing: gating + x->bf16 + d_out zeroing (standalone again; r8's merge
// capped the transpose occupancy at route's VGPR count) -------
__global__ __launch_bounds__(256) void route_kernel(
    const float* __restrict__ x, const float* __restrict__ Wg,
    int* __restrict__ counts, int* __restrict__ lists, float* __restrict__ pw,
    unsigned short* __restrict__ xb, float* __restrict__ outz)
{
    // fold d_out zeroing: 2048 blocks x 256 thr x 16 floats = 8192*1024 exactly.
    {
        size_t base = ((size_t)blockIdx.x * 256 + threadIdx.x) * 16;
        float4 z = {0.f, 0.f, 0.f, 0.f};
#pragma unroll
        for (int j = 0; j < 4; ++j)
            *reinterpret_cast<float4*>(outz + base + j * 4) = z;
    }

    int tok  = (int)((blockIdx.x * 256 + threadIdx.x) >> 6);
    int lane = threadIdx.x & 63;

    const float* xr = x + (size_t)tok * DM;
    unsigned short* xrow = xb ? (xb + (size_t)tok * DM) : nullptr;

    float acc[NE];
#pragma unroll
    for (int e = 0; e < NE; ++e) acc[e] = 0.f;

#pragma unroll
    for (int s = 0; s < 4; ++s) {
        int i = s * 256 + lane * 4;
        float4 xv = *reinterpret_cast<const float4*>(xr + i);
#pragma unroll
        for (int j = 0; j < 4; ++j) {
            const float* wr = Wg + (size_t)(i + j) * NE;
            float4 w0 = *reinterpret_cast<const float4*>(wr);
            float4 w1 = *reinterpret_cast<const float4*>(wr + 4);
            float xs = (j == 0) ? xv.x : (j == 1) ? xv.y : (j == 2) ? xv.z : xv.w;
            acc[0] += xs * w0.x; acc[1] += xs * w0.y;
            acc[2] += xs * w0.z; acc[3] += xs * w0.w;
            acc[4] += xs * w1.x; acc[5] += xs * w1.y;
            acc[6] += xs * w1.z; acc[7] += xs * w1.w;
        }
        if (xrow) {
            u16x4 o;
            o[0] = f2bf(xv.x); o[1] = f2bf(xv.y); o[2] = f2bf(xv.z); o[3] = f2bf(xv.w);
            *reinterpret_cast<u16x4*>(xrow + i) = o;
        }
    }

#pragma unroll
    for (int e = 0; e < NE; ++e) {
#pragma unroll
        for (int off = 32; off > 0; off >>= 1)
            acc[e] += __shfl_xor(acc[e], off, 64);
    }

    if (lane == 0) {
        int i0 = 0; float v0 = acc[0];
#pragma unroll
        for (int e = 1; e < NE; ++e) if (acc[e] > v0) { v0 = acc[e]; i0 = e; }
        int i1 = -1; float v1 = -INFINITY;
#pragma unroll
        for (int e = 0; e < NE; ++e) if (e != i0 && acc[e] > v1) { v1 = acc[e]; i1 = e; }
        float e1 = __expf(v1 - v0);
        float s  = 1.f + e1;
        int p0 = tok * 2, p1 = tok * 2 + 1;
        pw[p0] = 1.f / s;
        pw[p1] = e1 / s;
        int pos0 = atomicAdd(&counts[i0], 1);
        lists[i0 * T_TOK + pos0] = p0;
        int pos1 = atomicAdd(&counts[i1], 1);
        lists[i1 * T_TOK + pos1] = p1;
    }
}

// -------- big-tile W transpose: [E][K][N] fp32 -> [E][N][K] bf16, 128x128/block -----
// Old version: 16K tiny blocks, 4 loads+2 stores/thread, 128-256B chunks -> ~2 TB/s.
// New: 4096 blocks; per thread 16 independent float4 loads (deep MLP), 512B/row
// reads, 256B-contiguous-per-thread writes; LDS [128][136] u16 (34.8KB -> 4
// blocks/CU, 16 waves). Phase-2 scalar gathers are ~4-way banked (immaterial:
// LDS time << HBM time per block).
__global__ __launch_bounds__(256) void transpose_big(
    const float* __restrict__ W1, const float* __restrict__ W2,
    unsigned short* __restrict__ w1t, unsigned short* __restrict__ w2t)
{
    __shared__ unsigned short t[128][136];
    int id = blockIdx.x;
    const float* W; unsigned short* Wt; int K, N, e, k0, n0;
    if (id < 2048) {           // W1: K=1024,N=4096 -> 8 k-tiles x 32 n-tiles = 256/e
        W = W1; Wt = w1t; K = DM; N = DF;
        e = id >> 8; int r = id & 255;
        k0 = (r & 7) * 128; n0 = (r >> 3) * 128;
    } else {                   // W2: K=4096,N=1024 -> 32 k-tiles x 8 n-tiles = 256/e
        id -= 2048;
        W = W2; Wt = w2t; K = DF; N = DM;
        e = id >> 8; int r = id & 255;
        k0 = (r >> 3) * 128; n0 = (r & 7) * 128;
    }
    const float* We = W + (size_t)e * K * N + (size_t)k0 * N + n0;
    unsigned short* Wte = Wt + (size_t)e * K * N;

    int tid = threadIdx.x;
    int kr  = tid >> 5;                 // 0..7
    int n4  = (tid & 31) * 4;           // 0..124
#pragma unroll
    for (int i = 0; i < 16; ++i) {
        int k = kr + i * 8;             // 0..127
        float4 v = *reinterpret_cast<const float4*>(We + (size_t)k * N + n4);
        u16x4 o;
        o[0] = f2bf(v.x); o[1] = f2bf(v.y); o[2] = f2bf(v.z); o[3] = f2bf(v.w);
        *reinterpret_cast<u16x4*>(&t[k][n4]) = o;
    }
    __syncthreads();

    int n  = tid >> 1;                  // 0..127
    int kh = (tid & 1) * 64;            // 0 or 64
    unsigned short* dst = Wte + (size_t)(n0 + n) * K + k0 + kh;
#pragma unroll
    for (int s = 0; s < 8; ++s) {
        u16x8 o;
#pragma unroll
        for (int j = 0; j < 8; ++j) o[j] = t[kh + s * 8 + j][n];
        *reinterpret_cast<u16x8*>(dst + s * 8) = o;
    }
}

// ---------------- occupancy-first grouped GEMM (r8 core, frozen) ----------------
// BM=256, BN=128, BK=32, 512 thr, 8 waves (4M x 2N), per-wave 64x64.
// 2 blocks/CU = 16 waves/CU. Ring-3 slabs, depth-3 prefetch, counted vmcnt(6).
// LDS 72 KB: A 3x16K + B 3x8K. Swizzle (0 conflicts measured): store granule
// (tid&3)^((tid>>3)&3), read slot l4^((l15>>1)&3). Self-derived table from counts.
// pw folded into G1's silu epilogue ((w*h)@W2 == w*(h@W2), exact); G2 bare atomicAdd.
template<int N, int K, int SPLITK, bool IS_G1>
__global__ __launch_bounds__(512, 4) void moe_gemm15(
    const unsigned short* __restrict__ A,
    const unsigned short* __restrict__ Wt,
    const int* __restrict__ counts, const int* __restrict__ lists,
    const float* __restrict__ pw,
    unsigned short* __restrict__ Hout, float* __restrict__ Oout)
{
    constexpr int NT  = N / 128;
    constexpr int PAN = NT * SPLITK;
    constexpr int KS  = K / SPLITK;
    constexpr int NC  = KS / 32;
    static_assert(NC >= 4, "pipeline depth");

    __shared__ __attribute__((aligned(16))) char lds[73728];
    // A slot s: lds + s*16384 (256 rows x 64B); B slot s: lds + 49152 + s*8192

    int cnts[NE];
#pragma unroll
    for (int i = 0; i < NE; ++i) cnts[i] = counts[i];
    int ntl = 0;
#pragma unroll
    for (int i = 0; i < NE; ++i) ntl += (cnts[i] + 255) >> 8;

    int live = ntl * PAN;
    int orig = blockIdx.x;
    if (orig >= live) return;
    int q = live >> 3, r = live & 7;
    int xq = orig & 7, ib = orig >> 3;
    int work = (xq < r ? xq * (q + 1) : r * (q + 1) + (xq - r) * q) + ib;
    int rt    = work / PAN;                 // rt-major: neighbors share A-tile
    int panel = work - rt * PAN;
    int nt    = panel >> (SPLITK - 1);      // SPLITK is 1 or 2
    int sk    = panel & (SPLITK - 1);
    int koff  = sk * KS;

    // derive (e, slot0, off, cnt) from counts -- no offsets/table kernel
    int e = 0, tb = 0, off = 0, cnt = 0;
    {
        int ctb = 0, cob = 0; bool found = false;
#pragma unroll
        for (int i = 0; i < NE; ++i) {
            int ti = (cnts[i] + 255) >> 8;
            if (!found && rt < ctb + ti) { e = i; tb = ctb; off = cob; cnt = cnts[i]; found = true; }
            ctb += ti; cob += cnts[i];
        }
    }
    int slot0 = (rt - tb) << 8;
    int ntile = nt * 128;

    int tid  = threadIdx.x;
    int lane = tid & 63;
    int wid  = tid >> 6;
    int wm = wid >> 1;                  // 0..3
    int wn = wid & 1;                   // 0..1
    int l15 = lane & 15, l4 = lane >> 4;

    const unsigned short* Be = Wt + (size_t)e * N * K;

    // ---- staging offsets (elements). swizzle: granule ^= (row>>1)&3 ----
    int ssw = ((tid & 3) ^ ((tid >> 3) & 3)) * 8;
    unsigned aOff0, aOff1, bOff;
    {
        int r0 = tid >> 2;                  // 0..127
#pragma unroll
        for (int u = 0; u < 2; ++u) {
            int sl = slot0 + u * 128 + r0;
            unsigned grow;
            if (IS_G1) grow = (sl < cnt) ? (unsigned)(lists[e * T_TOK + sl] >> 1) : 0u;
            else       grow = (unsigned)(off + ((sl < cnt) ? sl : slot0));
            unsigned v = grow * (unsigned)K + (unsigned)(koff + ssw);
            if (u == 0) aOff0 = v; else aOff1 = v;
        }
        bOff = (unsigned)(ntile + r0) * (unsigned)K + (unsigned)(koff + ssw);
    }

    auto stage = [&](int s, int c) {
        int ko = c * 32;
        char* dA = lds + s * 16384 + tid * 16;
        char* dB = lds + 49152 + s * 8192 + tid * 16;
        GLDS16(A + aOff0 + ko, dA);
        GLDS16(A + aOff1 + ko, dA + 8192);
        GLDS16(Be + bOff + ko, dB);
    };

    // ---- fragment read bases (swizzled; row stride 64B) ----
    int swzb = (l4 ^ ((l15 >> 1) & 3)) * 16;
    int aRd = (wm * 64 + l15) * 64 + swzb;
    int bRd = (wn * 64 + l15) * 64 + swzb;

    f32x4 acc[4][4];
#pragma unroll
    for (int m = 0; m < 4; ++m)
#pragma unroll
        for (int n = 0; n < 4; ++n) acc[m][n] = (f32x4){0.f, 0.f, 0.f, 0.f};

    auto compute = [&](int s) {
        const char* Ab = lds + s * 16384;
        const char* Bb = lds + 49152 + s * 8192;
        s16x8 af[4];
#pragma unroll
        for (int m = 0; m < 4; ++m)
            af[m] = *reinterpret_cast<const s16x8*>(Ab + aRd + m * 1024);
        __builtin_amdgcn_s_setprio(1);
#pragma unroll
        for (int n = 0; n < 4; ++n) {
            s16x8 bf = *reinterpret_cast<const s16x8*>(Bb + bRd + n * 1024);
#pragma unroll
            for (int m = 0; m < 4; ++m)
                acc[m][n] = __builtin_amdgcn_mfma_f32_16x16x32_bf16(af[m], bf, acc[m][n], 0, 0, 0);
        }
        __builtin_amdgcn_s_setprio(0);
    };

    // ---- pipeline: 3-slot ring, depth-3 prefetch, counted vmcnt(6) ----
    stage(0, 0); stage(1, 1); stage(2, 2);
    int sslot = 0;
    for (int c = 0; c < NC; ++c) {
        if (c + 2 < NC)      waitvm<6>();   // chunk c done; c+1,c+2 in flight
        else if (c + 1 < NC) waitvm<3>();
        else                 waitvm<0>();
        BAR();
        compute(sslot);
        BAR();
        if (c + 3 < NC) stage(sslot, c + 3);
        sslot = (sslot == 2) ? 0 : sslot + 1;
    }

    // ---- epilogue: C/D col = lane&15, row = (lane>>4)*4 + rr ----
#pragma unroll
    for (int m = 0; m < 4; ++m) {
        int trow = wm * 64 + m * 16 + l4 * 4;
#pragma unroll
        for (int rr = 0; rr < 4; ++rr) {
            int slot = slot0 + trow + rr;
            if (slot >= cnt) continue;
            if (IS_G1) {
                int p = lists[e * T_TOK + slot];
                float w = pw[p];                 // gate folded into H (exact)
                unsigned short* hr = Hout + (size_t)(off + slot) * N;
#pragma unroll
                for (int n = 0; n < 4; ++n) {
                    int col = ntile + wn * 64 + n * 16 + l15;
                    float v = acc[m][n][rr];
                    float s = w * (v / (1.f + __expf(-v)));
                    hr[col] = f2bf(s);
                }
            } else {
                int p = lists[e * T_TOK + slot];
                float* orow = Oout + (size_t)(p >> 1) * DM;
#pragma unroll
                for (int n = 0; n < 4; ++n) {
                    int col = ntile + wn * 64 + n * 16 + l15;
                    atomicAdd(orow + col, acc[m][n][rr]);
                }
            }
        }
    }
}

// ================= fallback (round-1 validated fp32 path) =================
#define BMF 16
#define BFF 256
__global__ __launch_bounds__(256) void expert_gemm_f32(
    const float* __restrict__ x, const float* __restrict__ W1, const float* __restrict__ W2,
    const int* __restrict__ counts, const int* __restrict__ lists, const float* __restrict__ pw,
    float* __restrict__ out)
{
    int e    = blockIdx.y;
    int tile = blockIdx.x;
    int cnt  = counts[e];
    int start = tile * BMF;
    if (start >= cnt) return;

    __shared__ float xs[BMF][DM];
    __shared__ float hs[BMF][BFF];
    __shared__ int   toks[BMF];
    __shared__ float wgt[BMF];

    int tid = threadIdx.x;
    int nm  = cnt - start; if (nm > BMF) nm = BMF;

    if (tid < BMF) {
        if (tid < nm) {
            int p = lists[e * T_TOK + start + tid];
            toks[tid] = p >> 1;
            wgt[tid]  = pw[p];
        } else { toks[tid] = -1; wgt[tid] = 0.f; }
    }
    __syncthreads();
    for (int m = 0; m < BMF; ++m) {
        int t = toks[m];
        const float* xr = (t >= 0) ? (x + (size_t)t * DM) : nullptr;
        for (int i = tid; i < DM; i += 256) xs[m][i] = (t >= 0) ? xr[i] : 0.f;
    }
    __syncthreads();

    const float* W1e = W1 + (size_t)e * DM * DF;
    const float* W2e = W2 + (size_t)e * DF * DM;
    float acc[BMF][4];
#pragma unroll
    for (int m = 0; m < BMF; ++m)
#pragma unroll
        for (int c = 0; c < 4; ++c) acc[m][c] = 0.f;

    for (int fc = 0; fc < DF; fc += BFF) {
        float hacc[BMF];
#pragma unroll
        for (int m = 0; m < BMF; ++m) hacc[m] = 0.f;
        const float* w1col = W1e + fc + tid;
#pragma unroll 4
        for (int i = 0; i < DM; ++i) {
            float w1v = w1col[(size_t)i * DF];
#pragma unroll
            for (int m = 0; m < BMF; ++m) hacc[m] += xs[m][i] * w1v;
        }
        __syncthreads();
#pragma unroll
        for (int m = 0; m < BMF; ++m) {
            float v = hacc[m];
            hs[m][tid] = v / (1.f + __expf(-v));
        }
        __syncthreads();
        const float* w2base = W2e + (size_t)fc * DM + tid * 4;
        for (int f = 0; f < BFF; ++f) {
            float4 w2v = *reinterpret_cast<const float4*>(w2base + (size_t)f * DM);
#pragma unroll
            for (int m = 0; m < BMF; ++m) {
                float h = hs[m][f];
                acc[m][0] += h * w2v.x; acc[m][1] += h * w2v.y;
                acc[m][2] += h * w2v.z; acc[m][3] += h * w2v.w;
            }
        }
        __syncthreads();
    }
    int c0 = tid * 4;
#pragma unroll
    for (int m = 0; m < BMF; ++m) {
        int t = toks[m];
        if (t < 0) continue;
        float w = wgt[m];
        float* op = out + (size_t)t * DM + c0;
        atomicAdd(op + 0, w * acc[m][0]);
        atomicAdd(op + 1, w * acc[m][1]);
        atomicAdd(op + 2, w * acc[m][2]);
        atomicAdd(op + 3, w * acc[m][3]);
    }
}

// ================= launch =================
extern "C" void kernel_launch(void* const* d_in, const int* in_sizes, int n_in,
                              void* d_out, int out_size, void* d_ws, size_t ws_size,
                              hipStream_t stream)
{
    const float* x  = (const float*)d_in[0];
    const float* Wg = (const float*)d_in[1];
    const float* W1 = (const float*)d_in[2];
    const float* W2 = (const float*)d_in[3];
    float* out = (float*)d_out;

    char* ws = (char*)d_ws;
    int*      counts  = (int*)(ws + 0);
    int*      lists   = (int*)(ws + 2048);            // 256 KB
    float*    pw      = (float*)(ws + 2048 + 262144); // 64 KB

    const size_t o_xb  = 524288;
    const size_t sz_xb = (size_t)T_TOK * DM * 2;              // 16 MB
    const size_t o_w1t = o_xb + sz_xb;
    const size_t sz_w  = (size_t)NE * DM * DF * 2;            // 64 MB each
    const size_t o_w2t = o_w1t + sz_w;
    const size_t o_h   = o_w2t + sz_w;
    const size_t sz_h  = (size_t)(2 * T_TOK) * DF * 2;        // 134 MB
    const size_t NEEDED = o_h + sz_h;

    bool fast = (ws_size >= NEEDED);
    unsigned short* xb  = fast ? (unsigned short*)(ws + o_xb)  : nullptr;
    unsigned short* w1t = fast ? (unsigned short*)(ws + o_w1t) : nullptr;
    unsigned short* w2t = fast ? (unsigned short*)(ws + o_w2t) : nullptr;

    hipMemsetAsync(counts, 0, 64, stream);
    route_kernel<<<T_TOK / 4, 256, 0, stream>>>(x, Wg, counts, lists, pw, xb, out);

    if (fast) {
        unsigned short* H = (unsigned short*)(ws + o_h);
        transpose_big<<<4096, 256, 0, stream>>>(W1, W2, w1t, w2t);
        // G1: [cnt x 1024] @ W1t -> silu*gate -> H (bf16), 256x128 tiles
        moe_gemm15<DF, DM, 1, true><<<dim3(MAXT * 32), 512, 0, stream>>>(
            xb, w1t, counts, lists, pw, H, nullptr);
        // G2: H @ W2t -> atomic-add into out (gate pre-applied), split-K 2
        moe_gemm15<DM, DF, 2, false><<<dim3(MAXT * 16), 512, 0, stream>>>(
            H, w2t, counts, lists, pw, nullptr, out);
    } else {
        dim3 grid(T_TOK / BMF, NE);
        expert_gemm_f32<<<grid, 256, 0, stream>>>(x, W1, W2, counts, lists, pw, out);
    }
}

// Round 10
// 670.281 us; speedup vs baseline: 1.0218x; 1.0218x over previous
//
#include <hip/hip_runtime.h>
#include <hip/hip_bf16.h>
#include <math.h>

#define T_TOK 8192
#define DM 1024
#define DF 4096
#define NE 8
#define MAXT 72    // max 256-row tiles: 64 full + 7 partials + slack

typedef __attribute__((ext_vector_type(4))) float  f32x4;
typedef __attribute__((ext_vector_type(8))) short  s16x8;
typedef __attribute__((ext_vector_type(8))) unsigned short u16x8;
typedef __attribute__((ext_vector_type(4))) unsigned short u16x4;

__device__ __forceinline__ unsigned short f2bf(float f) {
    unsigned int u = __builtin_bit_cast(unsigned int, f);
    u = (u + 0x7FFFu + ((u >> 16) & 1u)) >> 16;
    return (unsigned short)u;
}

#define GLDS16(gptr, lptr)                                                         \
    __builtin_amdgcn_global_load_lds(                                              \
        (const __attribute__((address_space(1))) void*)(gptr),                     \
        (__attribute__((address_space(3))) void*)(lptr), 16, 0, 0)

#define BAR() asm volatile("s_barrier" ::: "memory")

template<int W>
__device__ __forceinline__ void waitvm() {
    if constexpr (W == 6)      asm volatile("s_waitcnt vmcnt(6)" ::: "memory");
    else if constexpr (W == 3) asm volatile("s_waitcnt vmcnt(3)" ::: "memory");
    else                       asm volatile("s_waitcnt vmcnt(0)" ::: "memory");
}

// ======= prep kernel v2: BIG-TILE transposes + route, ONE launch =======
// ids 0..2047:    W1 transpose [E][1024][4096] fp32 -> [E][4096][1024] bf16 (128x128)
// ids 2048..4095: W2 transpose [E][4096][1024] fp32 -> [E][1024][4096] bf16 (128x128)
// ids 4096..6143: route role (gating + x->bf16 + d_out zeroing)
// r8/r9 A/B showed: merging roles is worth ~15-25us (BW role overlaps VALU role);
// big-tile transpose is worth ~50-100us (deep load window, 128B-contiguous writes).
// This combines both. Fallback (w1t==null, grid=2048): every id is a route id.
__global__ __launch_bounds__(256) void prep_kernel(
    const float* __restrict__ x, const float* __restrict__ Wg,
    const float* __restrict__ W1, const float* __restrict__ W2,
    int* __restrict__ counts, int* __restrict__ lists, float* __restrict__ pw,
    unsigned short* __restrict__ xb, unsigned short* __restrict__ w1t,
    unsigned short* __restrict__ w2t, float* __restrict__ outz)
{
    __shared__ unsigned short t[128][136];
    int id  = blockIdx.x;
    int tid = threadIdx.x;
    int rid = w1t ? (id - 4096) : id;       // route id, or negative -> transpose

    if (rid >= 0) {
        // ---------------- route role ----------------
        // fold d_out zeroing: 2048 route blocks x 256 thr x 16 floats = 8192*1024.
        {
            size_t base = ((size_t)rid * 256 + tid) * 16;
            float4 z = {0.f, 0.f, 0.f, 0.f};
#pragma unroll
            for (int j = 0; j < 4; ++j)
                *reinterpret_cast<float4*>(outz + base + j * 4) = z;
        }

        int tok  = (int)((rid * 256 + tid) >> 6);
        int lane = tid & 63;

        const float* xr = x + (size_t)tok * DM;
        unsigned short* xrow = xb ? (xb + (size_t)tok * DM) : nullptr;

        float acc[NE];
#pragma unroll
        for (int e = 0; e < NE; ++e) acc[e] = 0.f;

#pragma unroll
        for (int s = 0; s < 4; ++s) {
            int i = s * 256 + lane * 4;
            float4 xv = *reinterpret_cast<const float4*>(xr + i);
#pragma unroll
            for (int j = 0; j < 4; ++j) {
                const float* wr = Wg + (size_t)(i + j) * NE;
                float4 w0 = *reinterpret_cast<const float4*>(wr);
                float4 w1 = *reinterpret_cast<const float4*>(wr + 4);
                float xs = (j == 0) ? xv.x : (j == 1) ? xv.y : (j == 2) ? xv.z : xv.w;
                acc[0] += xs * w0.x; acc[1] += xs * w0.y;
                acc[2] += xs * w0.z; acc[3] += xs * w0.w;
                acc[4] += xs * w1.x; acc[5] += xs * w1.y;
                acc[6] += xs * w1.z; acc[7] += xs * w1.w;
            }
            if (xrow) {
                u16x4 o;
                o[0] = f2bf(xv.x); o[1] = f2bf(xv.y); o[2] = f2bf(xv.z); o[3] = f2bf(xv.w);
                *reinterpret_cast<u16x4*>(xrow + i) = o;
            }
        }

#pragma unroll
        for (int e = 0; e < NE; ++e) {
#pragma unroll
            for (int off = 32; off > 0; off >>= 1)
                acc[e] += __shfl_xor(acc[e], off, 64);
        }

        if (lane == 0) {
            int i0 = 0; float v0 = acc[0];
#pragma unroll
            for (int e = 1; e < NE; ++e) if (acc[e] > v0) { v0 = acc[e]; i0 = e; }
            int i1 = -1; float v1 = -INFINITY;
#pragma unroll
            for (int e = 0; e < NE; ++e) if (e != i0 && acc[e] > v1) { v1 = acc[e]; i1 = e; }
            float e1 = __expf(v1 - v0);
            float s  = 1.f + e1;
            int p0 = tok * 2, p1 = tok * 2 + 1;
            pw[p0] = 1.f / s;
            pw[p1] = e1 / s;
            int pos0 = atomicAdd(&counts[i0], 1);
            lists[i0 * T_TOK + pos0] = p0;
            int pos1 = atomicAdd(&counts[i1], 1);
            lists[i1 * T_TOK + pos1] = p1;
        }
        return;
    }

    // ---------------- big-tile transpose roles (ids 0..4095) ----------------
    const float* W; unsigned short* Wt; int K, N, e, k0, n0;
    if (id < 2048) {           // W1: K=1024,N=4096 -> 8 k-tiles x 32 n-tiles = 256/e
        W = W1; Wt = w1t; K = DM; N = DF;
        e = id >> 8; int r = id & 255;
        k0 = (r & 7) * 128; n0 = (r >> 3) * 128;
    } else {                   // W2: K=4096,N=1024 -> 32 k-tiles x 8 n-tiles = 256/e
        int wid = id - 2048;
        W = W2; Wt = w2t; K = DF; N = DM;
        e = wid >> 8; int r = wid & 255;
        k0 = (r >> 3) * 128; n0 = (r & 7) * 128;
    }
    const float* We = W + (size_t)e * K * N + (size_t)k0 * N + n0;
    unsigned short* Wte = Wt + (size_t)e * K * N;

    int kr = tid >> 5;                  // 0..7
    int n4 = (tid & 31) * 4;            // 0..124
#pragma unroll
    for (int i = 0; i < 16; ++i) {
        int k = kr + i * 8;             // 0..127
        float4 v = *reinterpret_cast<const float4*>(We + (size_t)k * N + n4);
        u16x4 o;
        o[0] = f2bf(v.x); o[1] = f2bf(v.y); o[2] = f2bf(v.z); o[3] = f2bf(v.w);
        *reinterpret_cast<u16x4*>(&t[k][n4]) = o;
    }
    __syncthreads();

    int n  = tid >> 1;                  // 0..127
    int kh = (tid & 1) * 64;            // 0 or 64
    unsigned short* dst = Wte + (size_t)(n0 + n) * K + k0 + kh;
#pragma unroll
    for (int s = 0; s < 8; ++s) {
        u16x8 o;
#pragma unroll
        for (int j = 0; j < 8; ++j) o[j] = t[kh + s * 8 + j][n];
        *reinterpret_cast<u16x8*>(dst + s * 8) = o;
    }
}

// ---------------- occupancy-first grouped GEMM (frozen since r7) ----------------
// BM=256, BN=128, BK=32, 512 thr, 8 waves (4M x 2N), per-wave 64x64.
// 2 blocks/CU = 16 waves/CU. Ring-3 slabs, depth-3 prefetch, counted vmcnt(6).
// LDS 72 KB: A 3x16K + B 3x8K. Swizzle (0 conflicts measured): store granule
// (tid&3)^((tid>>3)&3), read slot l4^((l15>>1)&3). Self-derived table from counts.
// pw folded into G1's silu epilogue ((w*h)@W2 == w*(h@W2), exact); G2 bare atomicAdd.
template<int N, int K, int SPLITK, bool IS_G1>
__global__ __launch_bounds__(512, 4) void moe_gemm15(
    const unsigned short* __restrict__ A,
    const unsigned short* __restrict__ Wt,
    const int* __restrict__ counts, const int* __restrict__ lists,
    const float* __restrict__ pw,
    unsigned short* __restrict__ Hout, float* __restrict__ Oout)
{
    constexpr int NT  = N / 128;
    constexpr int PAN = NT * SPLITK;
    constexpr int KS  = K / SPLITK;
    constexpr int NC  = KS / 32;
    static_assert(NC >= 4, "pipeline depth");

    __shared__ __attribute__((aligned(16))) char lds[73728];
    // A slot s: lds + s*16384 (256 rows x 64B); B slot s: lds + 49152 + s*8192

    int cnts[NE];
#pragma unroll
    for (int i = 0; i < NE; ++i) cnts[i] = counts[i];
    int ntl = 0;
#pragma unroll
    for (int i = 0; i < NE; ++i) ntl += (cnts[i] + 255) >> 8;

    int live = ntl * PAN;
    int orig = blockIdx.x;
    if (orig >= live) return;
    int q = live >> 3, r = live & 7;
    int xq = orig & 7, ib = orig >> 3;
    int work = (xq < r ? xq * (q + 1) : r * (q + 1) + (xq - r) * q) + ib;
    int rt    = work / PAN;                 // rt-major: neighbors share A-tile
    int panel = work - rt * PAN;
    int nt    = panel >> (SPLITK - 1);      // SPLITK is 1 or 2
    int sk    = panel & (SPLITK - 1);
    int koff  = sk * KS;

    // derive (e, slot0, off, cnt) from counts -- no offsets/table kernel
    int e = 0, tb = 0, off = 0, cnt = 0;
    {
        int ctb = 0, cob = 0; bool found = false;
#pragma unroll
        for (int i = 0; i < NE; ++i) {
            int ti = (cnts[i] + 255) >> 8;
            if (!found && rt < ctb + ti) { e = i; tb = ctb; off = cob; cnt = cnts[i]; found = true; }
            ctb += ti; cob += cnts[i];
        }
    }
    int slot0 = (rt - tb) << 8;
    int ntile = nt * 128;

    int tid  = threadIdx.x;
    int lane = tid & 63;
    int wid  = tid >> 6;
    int wm = wid >> 1;                  // 0..3
    int wn = wid & 1;                   // 0..1
    int l15 = lane & 15, l4 = lane >> 4;

    const unsigned short* Be = Wt + (size_t)e * N * K;

    // ---- staging offsets (elements). swizzle: granule ^= (row>>1)&3 ----
    int ssw = ((tid & 3) ^ ((tid >> 3) & 3)) * 8;
    unsigned aOff0, aOff1, bOff;
    {
        int r0 = tid >> 2;                  // 0..127
#pragma unroll
        for (int u = 0; u < 2; ++u) {
            int sl = slot0 + u * 128 + r0;
            unsigned grow;
            if (IS_G1) grow = (sl < cnt) ? (unsigned)(lists[e * T_TOK + sl] >> 1) : 0u;
            else       grow = (unsigned)(off + ((sl < cnt) ? sl : slot0));
            unsigned v = grow * (unsigned)K + (unsigned)(koff + ssw);
            if (u == 0) aOff0 = v; else aOff1 = v;
        }
        bOff = (unsigned)(ntile + r0) * (unsigned)K + (unsigned)(koff + ssw);
    }

    auto stage = [&](int s, int c) {
        int ko = c * 32;
        char* dA = lds + s * 16384 + tid * 16;
        char* dB = lds + 49152 + s * 8192 + tid * 16;
        GLDS16(A + aOff0 + ko, dA);
        GLDS16(A + aOff1 + ko, dA + 8192);
        GLDS16(Be + bOff + ko, dB);
    };

    // ---- fragment read bases (swizzled; row stride 64B) ----
    int swzb = (l4 ^ ((l15 >> 1) & 3)) * 16;
    int aRd = (wm * 64 + l15) * 64 + swzb;
    int bRd = (wn * 64 + l15) * 64 + swzb;

    f32x4 acc[4][4];
#pragma unroll
    for (int m = 0; m < 4; ++m)
#pragma unroll
        for (int n = 0; n < 4; ++n) acc[m][n] = (f32x4){0.f, 0.f, 0.f, 0.f};

    auto compute = [&](int s) {
        const char* Ab = lds + s * 16384;
        const char* Bb = lds + 49152 + s * 8192;
        s16x8 af[4];
#pragma unroll
        for (int m = 0; m < 4; ++m)
            af[m] = *reinterpret_cast<const s16x8*>(Ab + aRd + m * 1024);
        __builtin_amdgcn_s_setprio(1);
#pragma unroll
        for (int n = 0; n < 4; ++n) {
            s16x8 bf = *reinterpret_cast<const s16x8*>(Bb + bRd + n * 1024);
#pragma unroll
            for (int m = 0; m < 4; ++m)
                acc[m][n] = __builtin_amdgcn_mfma_f32_16x16x32_bf16(af[m], bf, acc[m][n], 0, 0, 0);
        }
        __builtin_amdgcn_s_setprio(0);
    };

    // ---- pipeline: 3-slot ring, depth-3 prefetch, counted vmcnt(6) ----
    stage(0, 0); stage(1, 1); stage(2, 2);
    int sslot = 0;
    for (int c = 0; c < NC; ++c) {
        if (c + 2 < NC)      waitvm<6>();   // chunk c done; c+1,c+2 in flight
        else if (c + 1 < NC) waitvm<3>();
        else                 waitvm<0>();
        BAR();
        compute(sslot);
        BAR();
        if (c + 3 < NC) stage(sslot, c + 3);
        sslot = (sslot == 2) ? 0 : sslot + 1;
    }

    // ---- epilogue: C/D col = lane&15, row = (lane>>4)*4 + rr ----
#pragma unroll
    for (int m = 0; m < 4; ++m) {
        int trow = wm * 64 + m * 16 + l4 * 4;
#pragma unroll
        for (int rr = 0; rr < 4; ++rr) {
            int slot = slot0 + trow + rr;
            if (slot >= cnt) continue;
            if (IS_G1) {
                int p = lists[e * T_TOK + slot];
                float w = pw[p];                 // gate folded into H (exact)
                unsigned short* hr = Hout + (size_t)(off + slot) * N;
#pragma unroll
                for (int n = 0; n < 4; ++n) {
                    int col = ntile + wn * 64 + n * 16 + l15;
                    float v = acc[m][n][rr];
                    float s = w * (v / (1.f + __expf(-v)));
                    hr[col] = f2bf(s);
                }
            } else {
                int p = lists[e * T_TOK + slot];
                float* orow = Oout + (size_t)(p >> 1) * DM;
#pragma unroll
                for (int n = 0; n < 4; ++n) {
                    int col = ntile + wn * 64 + n * 16 + l15;
                    atomicAdd(orow + col, acc[m][n][rr]);
                }
            }
        }
    }
}

// ================= fallback (round-1 validated fp32 path) =================
#define BMF 16
#define BFF 256
__global__ __launch_bounds__(256) void expert_gemm_f32(
    const float* __restrict__ x, const float* __restrict__ W1, const float* __restrict__ W2,
    const int* __restrict__ counts, const int* __restrict__ lists, const float* __restrict__ pw,
    float* __restrict__ out)
{
    int e    = blockIdx.y;
    int tile = blockIdx.x;
    int cnt  = counts[e];
    int start = tile * BMF;
    if (start >= cnt) return;

    __shared__ float xs[BMF][DM];
    __shared__ float hs[BMF][BFF];
    __shared__ int   toks[BMF];
    __shared__ float wgt[BMF];

    int tid = threadIdx.x;
    int nm  = cnt - start; if (nm > BMF) nm = BMF;

    if (tid < BMF) {
        if (tid < nm) {
            int p = lists[e * T_TOK + start + tid];
            toks[tid] = p >> 1;
            wgt[tid]  = pw[p];
        } else { toks[tid] = -1; wgt[tid] = 0.f; }
    }
    __syncthreads();
    for (int m = 0; m < BMF; ++m) {
        int t = toks[m];
        const float* xr = (t >= 0) ? (x + (size_t)t * DM) : nullptr;
        for (int i = tid; i < DM; i += 256) xs[m][i] = (t >= 0) ? xr[i] : 0.f;
    }
    __syncthreads();

    const float* W1e = W1 + (size_t)e * DM * DF;
    const float* W2e = W2 + (size_t)e * DF * DM;
    float acc[BMF][4];
#pragma unroll
    for (int m = 0; m < BMF; ++m)
#pragma unroll
        for (int c = 0; c < 4; ++c) acc[m][c] = 0.f;

    for (int fc = 0; fc < DF; fc += BFF) {
        float hacc[BMF];
#pragma unroll
        for (int m = 0; m < BMF; ++m) hacc[m] = 0.f;
        const float* w1col = W1e + fc + tid;
#pragma unroll 4
        for (int i = 0; i < DM; ++i) {
            float w1v = w1col[(size_t)i * DF];
#pragma unroll
            for (int m = 0; m < BMF; ++m) hacc[m] += xs[m][i] * w1v;
        }
        __syncthreads();
#pragma unroll
        for (int m = 0; m < BMF; ++m) {
            float v = hacc[m];
            hs[m][tid] = v / (1.f + __expf(-v));
        }
        __syncthreads();
        const float* w2base = W2e + (size_t)fc * DM + tid * 4;
        for (int f = 0; f < BFF; ++f) {
            float4 w2v = *reinterpret_cast<const float4*>(w2base + (size_t)f * DM);
#pragma unroll
            for (int m = 0; m < BMF; ++m) {
                float h = hs[m][f];
                acc[m][0] += h * w2v.x; acc[m][1] += h * w2v.y;
                acc[m][2] += h * w2v.z; acc[m][3] += h * w2v.w;
            }
        }
        __syncthreads();
    }
    int c0 = tid * 4;
#pragma unroll
    for (int m = 0; m < BMF; ++m) {
        int t = toks[m];
        if (t < 0) continue;
        float w = wgt[m];
        float* op = out + (size_t)t * DM + c0;
        atomicAdd(op + 0, w * acc[m][0]);
        atomicAdd(op + 1, w * acc[m][1]);
        atomicAdd(op + 2, w * acc[m][2]);
        atomicAdd(op + 3, w * acc[m][3]);
    }
}

// ================= launch =================
extern "C" void kernel_launch(void* const* d_in, const int* in_sizes, int n_in,
                              void* d_out, int out_size, void* d_ws, size_t ws_size,
                              hipStream_t stream)
{
    const float* x  = (const float*)d_in[0];
    const float* Wg = (const float*)d_in[1];
    const float* W1 = (const float*)d_in[2];
    const float* W2 = (const float*)d_in[3];
    float* out = (float*)d_out;

    char* ws = (char*)d_ws;
    int*      counts  = (int*)(ws + 0);
    int*      lists   = (int*)(ws + 2048);            // 256 KB
    float*    pw      = (float*)(ws + 2048 + 262144); // 64 KB

    const size_t o_xb  = 524288;
    const size_t sz_xb = (size_t)T_TOK * DM * 2;              // 16 MB
    const size_t o_w1t = o_xb + sz_xb;
    const size_t sz_w  = (size_t)NE * DM * DF * 2;            // 64 MB each
    const size_t o_w2t = o_w1t + sz_w;
    const size_t o_h   = o_w2t + sz_w;
    const size_t sz_h  = (size_t)(2 * T_TOK) * DF * 2;        // 134 MB
    const size_t NEEDED = o_h + sz_h;

    bool fast = (ws_size >= NEEDED);
    unsigned short* xb  = fast ? (unsigned short*)(ws + o_xb)  : nullptr;
    unsigned short* w1t = fast ? (unsigned short*)(ws + o_w1t) : nullptr;
    unsigned short* w2t = fast ? (unsigned short*)(ws + o_w2t) : nullptr;

    hipMemsetAsync(counts, 0, 64, stream);
    // one launch: big-tile W transposes (ids 0..4095) + route (ids 4096..6143)
    prep_kernel<<<fast ? 6144 : 2048, 256, 0, stream>>>(
        x, Wg, W1, W2, counts, lists, pw, xb, w1t, w2t, out);

    if (fast) {
        unsigned short* H = (unsigned short*)(ws + o_h);
        // G1: [cnt x 1024] @ W1t -> silu*gate -> H (bf16), 256x128 tiles
        moe_gemm15<DF, DM, 1, true><<<dim3(MAXT * 32), 512, 0, stream>>>(
            xb, w1t, counts, lists, pw, H, nullptr);
        // G2: H @ W2t -> atomic-add into out (gate pre-applied), split-K 2
        moe_gemm15<DM, DF, 2, false><<<dim3(MAXT * 16), 512, 0, stream>>>(
            H, w2t, counts, lists, pw, nullptr, out);
    } else {
        dim3 grid(T_TOK / BMF, NE);
        expert_gemm_f32<<<grid, 256, 0, stream>>>(x, W1, W2, counts, lists, pw, out);
    }
}